// Round 1
// baseline (222.080 us; speedup 1.0000x reference)
//
#include <hip/hip_runtime.h>

#define NB 16           // B images
#define NP 16000        // proposals per image
#define NG 256          // gt boxes per image
#define NM (NP + NG)    // proposals + gt
#define NS 512          // samples per image
#define NCLS 91
#define FG_T 0.5f
#define SL1_BETA (1.0f/9.0f)

// ---------------------------------------------------------------------------
// Kernel 1: per-proposal max-IoU match against this image's 256 GT boxes.
// grid = (ceil(NM/256), NB), block = 256. GTs staged in LDS (broadcast reads).
// ---------------------------------------------------------------------------
__global__ void match_kernel(const float* __restrict__ proposals,
                             const float* __restrict__ gt_boxes,
                             const int*   __restrict__ gt_labels,
                             int* __restrict__ lbl_out,
                             int* __restrict__ match_out)
{
    __shared__ float gb0[NG], gb1[NG], gb2[NG], gb3[NG];
    __shared__ float garea[NG];
    __shared__ int   glab[NG];

    const int b   = blockIdx.y;
    const int tid = threadIdx.x;

    {   // 256 threads load 256 gts
        const float* s = gt_boxes + ((size_t)b * NG + tid) * 4;
        float x0 = s[0], y0 = s[1], x1 = s[2], y1 = s[3];
        gb0[tid] = x0; gb1[tid] = y0; gb2[tid] = x1; gb3[tid] = y1;
        garea[tid] = (x1 - x0) * (y1 - y0);
        glab[tid]  = gt_labels[b * NG + tid];
    }
    __syncthreads();

    const int j = blockIdx.x * 256 + tid;
    if (j >= NM) return;

    float p0, p1, p2, p3;
    if (j < NP) {
        const float* s = proposals + ((size_t)b * NP + j) * 4;
        p0 = s[0]; p1 = s[1]; p2 = s[2]; p3 = s[3];
    } else {
        int g = j - NP;
        p0 = gb0[g]; p1 = gb1[g]; p2 = gb2[g]; p3 = gb3[g];
    }
    const float ap = (p2 - p0) * (p3 - p1);

    float best = -1.0f;
    int   bi   = 0;
    #pragma unroll 4
    for (int g = 0; g < NG; ++g) {
        float lx = fmaxf(gb0[g], p0);
        float ly = fmaxf(gb1[g], p1);
        float rx = fminf(gb2[g], p2);
        float ry = fminf(gb3[g], p3);
        float w  = fmaxf(rx - lx, 0.0f);
        float h  = fmaxf(ry - ly, 0.0f);
        float inter = w * h;
        float iou   = inter / (garea[g] + ap - inter);
        if (iou > best) { best = iou; bi = g; }   // strict > keeps first max (argmax tie rule)
    }
    int l = (best < FG_T) ? 0 : glab[bi];         // FG_T==BG_T -> no ignore band
    lbl_out[(size_t)b * NM + j]   = l;
    match_out[(size_t)b * NM + j] = bi;
}

// ---------------------------------------------------------------------------
// Kernel 2: per-image balanced sampler (deterministic first-k) + box encoding.
// grid = NB, block = 256. Block-wide scan over 64 chunks of 256.
// ---------------------------------------------------------------------------
__global__ void sample_kernel(const float* __restrict__ proposals,
                              const float* __restrict__ gt_boxes,
                              const float* __restrict__ gt_thetas,
                              const int*   __restrict__ lbl_in,
                              const int*   __restrict__ match_in,
                              int*   __restrict__ labels_out,   // [NB*NS]
                              float* __restrict__ regt_out)     // [NB*NS*5]
{
    __shared__ int sc[256];
    __shared__ int posList[640];   // first-640 positives (covers all fill cases)
    __shared__ int negList[512];   // first-512 negatives
    __shared__ int sampled[NS];
    __shared__ int bases[2];

    const int b   = blockIdx.x;
    const int tid = threadIdx.x;
    const int* L  = lbl_in + (size_t)b * NM;

    if (tid == 0) { bases[0] = 0; bases[1] = 0; }
    __syncthreads();

    for (int c = 0; c < 64; ++c) {            // 64*256 = 16384 >= NM
        int t = c * 256 + tid;
        int l = (t < NM) ? L[t] : -2;
        int p = (l > 0) ? 1 : 0;
        int n = (l == 0) ? 1 : 0;
        int val = (p << 16) | n;

        int x = val;
        sc[tid] = x;
        __syncthreads();
        for (int off = 1; off < 256; off <<= 1) {
            int u = (tid >= off) ? sc[tid - off] : 0;
            __syncthreads();
            x += u;
            sc[tid] = x;
            __syncthreads();
        }
        int total = sc[255];
        int excl  = x - val;
        int pb = bases[0], nb = bases[1];
        if (p) { int r = pb + (excl >> 16);     if (r < 640) posList[r] = t; }
        if (n) { int r = nb + (excl & 0xffff);  if (r < 512) negList[r] = t; }
        __syncthreads();
        if (tid == 0) { bases[0] = pb + (total >> 16); bases[1] = nb + (total & 0xffff); }
        __syncthreads();
    }

    if (tid == 0) {
        int pos_total = bases[0];
        int neg_total = bases[1];
        int np = pos_total < 128 ? pos_total : 128;          // n_pos = min(pos, S*0.25)
        int nn = NS - np;  if (nn > neg_total) nn = neg_total;
        // merge ascending (== stable argsort of ~mask)
        int i = 0, a = 0, g = 0;
        while (a < np && g < nn) sampled[i++] = (posList[a] < negList[g]) ? posList[a++] : negList[g++];
        while (a < np) sampled[i++] = posList[a++];
        while (g < nn) sampled[i++] = negList[g++];
        // fill (only reachable if negatives are scarce): unselected positives, ascending
        int k = np;
        while (i < NS && k < 640) sampled[i++] = posList[k++];
    }
    __syncthreads();

    for (int i = tid; i < NS; i += 256) {
        int idx = sampled[i];
        int m   = match_in[(size_t)b * NM + idx];
        int l   = L[idx];
        float p0, p1, p2, p3;
        if (idx < NP) {
            const float* s = proposals + ((size_t)b * NP + idx) * 4;
            p0 = s[0]; p1 = s[1]; p2 = s[2]; p3 = s[3];
        } else {
            const float* s = gt_boxes + ((size_t)b * NG + (idx - NP)) * 4;
            p0 = s[0]; p1 = s[1]; p2 = s[2]; p3 = s[3];
        }
        const float* rf = gt_boxes + ((size_t)b * NG + m) * 4;
        float r0 = rf[0], r1 = rf[1], r2 = rf[2], r3 = rf[3];

        float pw = p2 - p0, ph = p3 - p1;
        float px = p0 + 0.5f * pw, py = p1 + 0.5f * ph;
        float gw = r2 - r0, gh = r3 - r1;
        float gx = r0 + 0.5f * gw, gy = r1 + 0.5f * gh;

        float* o = regt_out + ((size_t)b * NS + i) * 5;
        o[0] = 10.0f * (gx - px) / pw;
        o[1] = 10.0f * (gy - py) / ph;
        o[2] = 5.0f * logf(gw / pw);
        o[3] = 5.0f * logf(gh / ph);
        o[4] = gt_thetas[b * NG + m];
        labels_out[b * NS + i] = l;
    }
}

// ---------------------------------------------------------------------------
// Kernel 3: fused CE (log-softmax over 91) + smooth-L1 box loss, atomics.
// One 64-lane wave per row; 4 rows per 256-thread block. grid = N/4.
// ---------------------------------------------------------------------------
__global__ void loss_kernel(const float* __restrict__ logits,     // [N, 91]
                            const float* __restrict__ boxreg,     // [N, 455]
                            const int*   __restrict__ labels,     // [N]
                            const float* __restrict__ regt,       // [N, 5]
                            float* __restrict__ acc)              // [2]
{
    const int wave = threadIdx.x >> 6;
    const int lane = threadIdx.x & 63;
    const int r    = blockIdx.x * 4 + wave;

    const float* row = logits + (size_t)r * NCLS;
    float a = (lane < NCLS)      ? row[lane]      : -3.0e38f;
    float c = (lane + 64 < NCLS) ? row[lane + 64] : -3.0e38f;
    float mx = fmaxf(a, c);
    for (int o = 32; o; o >>= 1) mx = fmaxf(mx, __shfl_xor(mx, o, 64));
    float s = 0.0f;
    if (lane < NCLS)      s += expf(a - mx);
    if (lane + 64 < NCLS) s += expf(c - mx);
    for (int o = 32; o; o >>= 1) s += __shfl_xor(s, o, 64);

    __shared__ float cpart[4], bpart[4];
    if (lane == 0) {
        int lab = labels[r];
        float xl = row[lab];
        float cls = -(xl - mx - logf(s));
        float bl = 0.0f;
        if (lab > 0) {
            const float* pr = boxreg + (size_t)r * (NCLS * 5) + lab * 5;
            const float* tg = regt + (size_t)r * 5;
            #pragma unroll
            for (int k = 0; k < 5; ++k) {
                float d  = pr[k] - tg[k];
                float ad = fabsf(d);
                bl += (ad < SL1_BETA) ? 0.5f * d * d / SL1_BETA : ad - 0.5f * SL1_BETA;
            }
        }
        cpart[wave] = cls; bpart[wave] = bl;
    }
    __syncthreads();
    if (threadIdx.x == 0) {
        atomicAdd(&acc[0], cpart[0] + cpart[1] + cpart[2] + cpart[3]);
        atomicAdd(&acc[1], bpart[0] + bpart[1] + bpart[2] + bpart[3]);
    }
}

__global__ void init_kernel(float* acc) {
    if (threadIdx.x < 2) acc[threadIdx.x] = 0.0f;
}

__global__ void final_kernel(const float* acc, float* out) {
    const float invN = 1.0f / (float)(NB * NS);
    out[0] = acc[0] * invN;
    out[1] = acc[1] * invN;
}

// ---------------------------------------------------------------------------
extern "C" void kernel_launch(void* const* d_in, const int* in_sizes, int n_in,
                              void* d_out, int out_size, void* d_ws, size_t ws_size,
                              hipStream_t stream)
{
    const float* class_logits   = (const float*)d_in[0];  // [NB*NS, 91]
    const float* box_regression = (const float*)d_in[1];  // [NB*NS, 455]
    const float* proposals      = (const float*)d_in[2];  // [NB, NP, 4]
    const float* gt_boxes       = (const float*)d_in[3];  // [NB, NG, 4]
    const float* gt_thetas      = (const float*)d_in[4];  // [NB, NG]
    const int*   gt_labels      = (const int*)d_in[5];    // [NB, NG]
    float* out = (float*)d_out;

    char* ws = (char*)d_ws;
    float* acc  = (float*)ws;                      // 2 floats (+pad)
    int* lblw   = (int*)(ws + 256);                // NB*NM
    int* matw   = lblw + (size_t)NB * NM;          // NB*NM
    int* labs   = matw + (size_t)NB * NM;          // NB*NS
    float* regt = (float*)(labs + (size_t)NB * NS);// NB*NS*5

    hipLaunchKernelGGL(init_kernel, dim3(1), dim3(64), 0, stream, acc);
    hipLaunchKernelGGL(match_kernel, dim3((NM + 255) / 256, NB), dim3(256), 0, stream,
                       proposals, gt_boxes, gt_labels, lblw, matw);
    hipLaunchKernelGGL(sample_kernel, dim3(NB), dim3(256), 0, stream,
                       proposals, gt_boxes, gt_thetas, lblw, matw, labs, regt);
    hipLaunchKernelGGL(loss_kernel, dim3((NB * NS) / 4), dim3(256), 0, stream,
                       class_logits, box_regression, labs, regt, acc);
    hipLaunchKernelGGL(final_kernel, dim3(1), dim3(1), 0, stream, acc, out);
}

// Round 2
// 114.896 us; speedup vs baseline: 1.9329x; 1.9329x over previous
//
#include <hip/hip_runtime.h>

#define NB 16           // B images
#define NP 16000        // proposals per image
#define NG 256          // gt boxes per image
#define NM (NP + NG)    // proposals + gt = 16256 = 254*64
#define NS 512          // samples per image
#define NCLS 91
#define FG_T 0.5f
#define SL1_BETA (1.0f/9.0f)

// ---------------------------------------------------------------------------
// Kernel 1: per-proposal max-IoU match against this image's 256 GT boxes.
// grid = (ceil(NM/256), NB), block = 256. GTs staged in LDS (broadcast reads).
// Division-free argmax: track (inter, union) of best; compare cross-products.
// One precise division at the end for the 0.5 threshold.
// ---------------------------------------------------------------------------
__global__ void match_kernel(const float* __restrict__ proposals,
                             const float* __restrict__ gt_boxes,
                             const int*   __restrict__ gt_labels,
                             int* __restrict__ lbl_out,
                             int* __restrict__ match_out)
{
    __shared__ float gb0[NG], gb1[NG], gb2[NG], gb3[NG];
    __shared__ float garea[NG];
    __shared__ int   glab[NG];

    const int b   = blockIdx.y;
    const int tid = threadIdx.x;

    {   // 256 threads load 256 gts
        const float* s = gt_boxes + ((size_t)b * NG + tid) * 4;
        float x0 = s[0], y0 = s[1], x1 = s[2], y1 = s[3];
        gb0[tid] = x0; gb1[tid] = y0; gb2[tid] = x1; gb3[tid] = y1;
        garea[tid] = (x1 - x0) * (y1 - y0);
        glab[tid]  = gt_labels[b * NG + tid];
    }
    __syncthreads();

    const int j = blockIdx.x * 256 + tid;
    if (j >= NM) return;

    float p0, p1, p2, p3;
    if (j < NP) {
        const float* s = proposals + ((size_t)b * NP + j) * 4;
        p0 = s[0]; p1 = s[1]; p2 = s[2]; p3 = s[3];
    } else {
        int g = j - NP;
        p0 = gb0[g]; p1 = gb1[g]; p2 = gb2[g]; p3 = gb3[g];
    }
    const float ap = (p2 - p0) * (p3 - p1);

    float ib = -1.0f, ub = 1.0f;   // best (inter, union); iou_best = ib/ub
    int   bi = 0;
    #pragma unroll 4
    for (int g = 0; g < NG; ++g) {
        float lx = fmaxf(gb0[g], p0);
        float ly = fmaxf(gb1[g], p1);
        float rx = fminf(gb2[g], p2);
        float ry = fminf(gb3[g], p3);
        float w  = fmaxf(rx - lx, 0.0f);
        float h  = fmaxf(ry - ly, 0.0f);
        float inter = w * h;
        float u  = (garea[g] + ap) - inter;          // same assoc as reference
        // inter/u > ib/ub  <=>  inter*ub > ib*u  (u, ub > 0)
        if (inter * ub > ib * u) { ib = inter; ub = u; bi = g; }
    }
    float best = ib / ub;                            // precise, for threshold
    int l = (best < FG_T) ? 0 : glab[bi];            // FG_T==BG_T -> no ignore band
    lbl_out[(size_t)b * NM + j]   = l;
    match_out[(size_t)b * NM + j] = bi;
}

// ---------------------------------------------------------------------------
// Kernel 2: per-image balanced sampler (deterministic first-k) + box encoding.
// grid = NB, block = 256. Each thread owns 64 CONTIGUOUS labels -> bitmasks,
// one shfl-based block scan (2 barriers), direct-slot writes (no merge):
//   selected positive (pos-rank rp) -> slot rp + min(negExcl, nn)
//   selected negative (neg-rank rn) -> slot rn + min(posExcl, np)
// ---------------------------------------------------------------------------
__global__ void sample_kernel(const float* __restrict__ proposals,
                              const float* __restrict__ gt_boxes,
                              const float* __restrict__ gt_thetas,
                              const int*   __restrict__ lbl_in,
                              const int*   __restrict__ match_in,
                              int*   __restrict__ labels_out,   // [NB*NS]
                              float* __restrict__ regt_out)     // [NB*NS*5]
{
    __shared__ int sampled[NS];
    __shared__ int wsum[4];

    const int b    = blockIdx.x;
    const int tid  = threadIdx.x;
    const int lane = tid & 63;
    const int wid  = tid >> 6;
    const int* L   = lbl_in + (size_t)b * NM;
    const int base = tid * 64;                 // threads 0..253 cover [0,NM)

    unsigned long long pmask = 0ull, nmask = 0ull;
    if (base < NM) {                           // full 64 in-range (NM = 254*64)
        const int4* Lv = reinterpret_cast<const int4*>(L + base);
        #pragma unroll
        for (int q = 0; q < 16; ++q) {
            int4 v = Lv[q];
            int e = q * 4;
            if (v.x > 0) pmask |= 1ull << (e + 0); else if (v.x == 0) nmask |= 1ull << (e + 0);
            if (v.y > 0) pmask |= 1ull << (e + 1); else if (v.y == 0) nmask |= 1ull << (e + 1);
            if (v.z > 0) pmask |= 1ull << (e + 2); else if (v.z == 0) nmask |= 1ull << (e + 2);
            if (v.w > 0) pmask |= 1ull << (e + 3); else if (v.w == 0) nmask |= 1ull << (e + 3);
        }
    }
    int cp = __popcll(pmask), cn = __popcll(nmask);
    int val  = (cp << 16) | cn;                // counts fit: NM < 65536
    int incl = val;
    #pragma unroll
    for (int off = 1; off < 64; off <<= 1) {
        int u = __shfl_up(incl, off, 64);
        if (lane >= off) incl += u;
    }
    if (lane == 63) wsum[wid] = incl;
    __syncthreads();
    int wbase = 0;
    #pragma unroll
    for (int w = 0; w < 4; ++w) if (w < wid) wbase += wsum[w];
    int tot  = wsum[0] + wsum[1] + wsum[2] + wsum[3];
    int excl = wbase + incl - val;
    int rp = excl >> 16, rn = excl & 0xffff;
    int posT = tot >> 16, negT = tot & 0xffff;
    int np = posT < 128 ? posT : 128;          // n_pos = min(pos_total, S/4)
    int nn = NS - np; if (nn > negT) nn = negT;

    if (base < NM) {
        #pragma unroll 4
        for (int e = 0; e < 64; ++e) {
            int idx = base + e;
            if ((pmask >> e) & 1ull) {
                if (rp < np) sampled[rp + (rn < nn ? rn : nn)] = idx;
                rp++;
            } else if ((nmask >> e) & 1ull) {
                if (rn < nn) sampled[rn + (rp < np ? rp : np)] = idx;
                rn++;
            }
        }
    }
    __syncthreads();
    // Fallback fill (unreachable with this data: pos>=NG, neg abundant):
    // unselected indices ascending, appended after the np+nn selected.
    if (tid == 0 && np + nn < NS) {
        int cpp = 0, cnn = 0, i = np + nn;
        for (int idx = 0; idx < NM && i < NS; ++idx) {
            int l = L[idx]; bool s;
            if (l > 0)       { s = cpp < np; cpp++; }
            else if (l == 0) { s = cnn < nn; cnn++; }
            else             { s = false; }
            if (!s) sampled[i++] = idx;
        }
    }
    __syncthreads();

    for (int i = tid; i < NS; i += 256) {
        int idx = sampled[i];
        int m   = match_in[(size_t)b * NM + idx];
        int l   = L[idx];
        float p0, p1, p2, p3;
        if (idx < NP) {
            const float* s = proposals + ((size_t)b * NP + idx) * 4;
            p0 = s[0]; p1 = s[1]; p2 = s[2]; p3 = s[3];
        } else {
            const float* s = gt_boxes + ((size_t)b * NG + (idx - NP)) * 4;
            p0 = s[0]; p1 = s[1]; p2 = s[2]; p3 = s[3];
        }
        const float* rf = gt_boxes + ((size_t)b * NG + m) * 4;
        float r0 = rf[0], r1 = rf[1], r2 = rf[2], r3 = rf[3];

        float pw = p2 - p0, ph = p3 - p1;
        float px = p0 + 0.5f * pw, py = p1 + 0.5f * ph;
        float gw = r2 - r0, gh = r3 - r1;
        float gx = r0 + 0.5f * gw, gy = r1 + 0.5f * gh;

        float* o = regt_out + ((size_t)b * NS + i) * 5;
        o[0] = 10.0f * (gx - px) / pw;
        o[1] = 10.0f * (gy - py) / ph;
        o[2] = 5.0f * logf(gw / pw);
        o[3] = 5.0f * logf(gh / ph);
        o[4] = gt_thetas[b * NG + m];
        labels_out[b * NS + i] = l;
    }
}

// ---------------------------------------------------------------------------
// Kernel 3: fused CE (log-softmax over 91) + smooth-L1 box loss, atomics.
// One 64-lane wave per row; 4 rows per 256-thread block. grid = N/4.
// ---------------------------------------------------------------------------
__global__ void loss_kernel(const float* __restrict__ logits,     // [N, 91]
                            const float* __restrict__ boxreg,     // [N, 455]
                            const int*   __restrict__ labels,     // [N]
                            const float* __restrict__ regt,       // [N, 5]
                            float* __restrict__ acc)              // [2]
{
    const int wave = threadIdx.x >> 6;
    const int lane = threadIdx.x & 63;
    const int r    = blockIdx.x * 4 + wave;

    const float* row = logits + (size_t)r * NCLS;
    float a = (lane < NCLS)      ? row[lane]      : -3.0e38f;
    float c = (lane + 64 < NCLS) ? row[lane + 64] : -3.0e38f;
    float mx = fmaxf(a, c);
    for (int o = 32; o; o >>= 1) mx = fmaxf(mx, __shfl_xor(mx, o, 64));
    float s = 0.0f;
    if (lane < NCLS)      s += expf(a - mx);
    if (lane + 64 < NCLS) s += expf(c - mx);
    for (int o = 32; o; o >>= 1) s += __shfl_xor(s, o, 64);

    __shared__ float cpart[4], bpart[4];
    if (lane == 0) {
        int lab = labels[r];
        float xl = row[lab];
        float cls = -(xl - mx - logf(s));
        float bl = 0.0f;
        if (lab > 0) {
            const float* pr = boxreg + (size_t)r * (NCLS * 5) + lab * 5;
            const float* tg = regt + (size_t)r * 5;
            #pragma unroll
            for (int k = 0; k < 5; ++k) {
                float d  = pr[k] - tg[k];
                float ad = fabsf(d);
                bl += (ad < SL1_BETA) ? 0.5f * d * d / SL1_BETA : ad - 0.5f * SL1_BETA;
            }
        }
        cpart[wave] = cls; bpart[wave] = bl;
    }
    __syncthreads();
    if (threadIdx.x == 0) {
        atomicAdd(&acc[0], cpart[0] + cpart[1] + cpart[2] + cpart[3]);
        atomicAdd(&acc[1], bpart[0] + bpart[1] + bpart[2] + bpart[3]);
    }
}

__global__ void init_kernel(float* acc) {
    if (threadIdx.x < 2) acc[threadIdx.x] = 0.0f;
}

__global__ void final_kernel(const float* acc, float* out) {
    const float invN = 1.0f / (float)(NB * NS);
    out[0] = acc[0] * invN;
    out[1] = acc[1] * invN;
}

// ---------------------------------------------------------------------------
extern "C" void kernel_launch(void* const* d_in, const int* in_sizes, int n_in,
                              void* d_out, int out_size, void* d_ws, size_t ws_size,
                              hipStream_t stream)
{
    const float* class_logits   = (const float*)d_in[0];  // [NB*NS, 91]
    const float* box_regression = (const float*)d_in[1];  // [NB*NS, 455]
    const float* proposals      = (const float*)d_in[2];  // [NB, NP, 4]
    const float* gt_boxes       = (const float*)d_in[3];  // [NB, NG, 4]
    const float* gt_thetas      = (const float*)d_in[4];  // [NB, NG]
    const int*   gt_labels      = (const int*)d_in[5];    // [NB, NG]
    float* out = (float*)d_out;

    char* ws = (char*)d_ws;
    float* acc  = (float*)ws;                      // 2 floats (+pad)
    int* lblw   = (int*)(ws + 256);                // NB*NM
    int* matw   = lblw + (size_t)NB * NM;          // NB*NM
    int* labs   = matw + (size_t)NB * NM;          // NB*NS
    float* regt = (float*)(labs + (size_t)NB * NS);// NB*NS*5

    hipLaunchKernelGGL(init_kernel, dim3(1), dim3(64), 0, stream, acc);
    hipLaunchKernelGGL(match_kernel, dim3((NM + 255) / 256, NB), dim3(256), 0, stream,
                       proposals, gt_boxes, gt_labels, lblw, matw);
    hipLaunchKernelGGL(sample_kernel, dim3(NB), dim3(256), 0, stream,
                       proposals, gt_boxes, gt_thetas, lblw, matw, labs, regt);
    hipLaunchKernelGGL(loss_kernel, dim3((NB * NS) / 4), dim3(256), 0, stream,
                       class_logits, box_regression, labs, regt, acc);
    hipLaunchKernelGGL(final_kernel, dim3(1), dim3(1), 0, stream, acc, out);
}

// Round 3
// 69.283 us; speedup vs baseline: 3.2054x; 1.6584x over previous
//
#include <hip/hip_runtime.h>

#define NB 16           // B images
#define NP 16000        // proposals per image
#define NG 256          // gt boxes per image
#define NM (NP + NG)    // proposals + gt = 16256 = 254*64
#define NS 512          // samples per image
#define NCLS 91
#define FG_T 0.5f
#define SL1_BETA (1.0f/9.0f)
#define LOSS_BLOCKS 256

// ---------------------------------------------------------------------------
// Kernel 1: per-proposal max-IoU match against this image's 256 GT boxes.
// grid = (ceil(NM/256), NB), block = 256. GTs staged in LDS as float4 so the
// inner loop is 1x ds_read_b128 + 1x broadcast ds_read_b32 per GT.
// Division-free argmax: compare cross-products; one division at the end.
// ---------------------------------------------------------------------------
__global__ void match_kernel(const float* __restrict__ proposals,
                             const float* __restrict__ gt_boxes,
                             const int*   __restrict__ gt_labels,
                             int* __restrict__ lbl_out,
                             int* __restrict__ match_out)
{
    __shared__ float4 gbox[NG];
    __shared__ float  garea[NG];
    __shared__ int    glab[NG];

    const int b   = blockIdx.y;
    const int tid = threadIdx.x;

    {   // 256 threads load 256 gts
        const float4 v = reinterpret_cast<const float4*>(gt_boxes)[(size_t)b * NG + tid];
        gbox[tid]  = v;
        garea[tid] = (v.z - v.x) * (v.w - v.y);
        glab[tid]  = gt_labels[b * NG + tid];
    }
    __syncthreads();

    const int j = blockIdx.x * 256 + tid;
    if (j >= NM) return;

    float p0, p1, p2, p3;
    if (j < NP) {
        const float4 v = reinterpret_cast<const float4*>(proposals)[(size_t)b * NP + j];
        p0 = v.x; p1 = v.y; p2 = v.z; p3 = v.w;
    } else {
        const float4 v = gbox[j - NP];
        p0 = v.x; p1 = v.y; p2 = v.z; p3 = v.w;
    }
    const float ap = (p2 - p0) * (p3 - p1);

    float ib = -1.0f, ub = 1.0f;   // best (inter, union); iou_best = ib/ub
    int   bi = 0;
    #pragma unroll 4
    for (int g = 0; g < NG; ++g) {
        float4 gb = gbox[g];
        float lx = fmaxf(gb.x, p0);
        float ly = fmaxf(gb.y, p1);
        float rx = fminf(gb.z, p2);
        float ry = fminf(gb.w, p3);
        float w  = fmaxf(rx - lx, 0.0f);
        float h  = fmaxf(ry - ly, 0.0f);
        float inter = w * h;
        float u  = (garea[g] + ap) - inter;          // same assoc as reference
        // inter/u > ib/ub  <=>  inter*ub > ib*u  (u, ub > 0)
        if (inter * ub > ib * u) { ib = inter; ub = u; bi = g; }
    }
    float best = ib / ub;                            // precise, for threshold
    int l = (best < FG_T) ? 0 : glab[bi];            // FG_T==BG_T -> no ignore band
    lbl_out[(size_t)b * NM + j]   = l;
    match_out[(size_t)b * NM + j] = bi;
}

// ---------------------------------------------------------------------------
// Kernel 2: per-image balanced sampler (deterministic first-k) + box encoding.
// grid = NB, block = 256. Each thread owns 64 CONTIGUOUS labels -> bitmasks,
// one shfl-based block scan (2 barriers), direct-slot writes (no merge):
//   selected positive (pos-rank rp) -> slot rp + min(negExcl, nn)
//   selected negative (neg-rank rn) -> slot rn + min(posExcl, np)
// ---------------------------------------------------------------------------
__global__ void sample_kernel(const float* __restrict__ proposals,
                              const float* __restrict__ gt_boxes,
                              const float* __restrict__ gt_thetas,
                              const int*   __restrict__ lbl_in,
                              const int*   __restrict__ match_in,
                              int*   __restrict__ labels_out,   // [NB*NS]
                              float* __restrict__ regt_out)     // [NB*NS*5]
{
    __shared__ int sampled[NS];
    __shared__ int wsum[4];

    const int b    = blockIdx.x;
    const int tid  = threadIdx.x;
    const int lane = tid & 63;
    const int wid  = tid >> 6;
    const int* L   = lbl_in + (size_t)b * NM;
    const int base = tid * 64;                 // threads 0..253 cover [0,NM)

    unsigned long long pmask = 0ull, nmask = 0ull;
    if (base < NM) {                           // full 64 in-range (NM = 254*64)
        const int4* Lv = reinterpret_cast<const int4*>(L + base);
        #pragma unroll
        for (int q = 0; q < 16; ++q) {
            int4 v = Lv[q];
            int e = q * 4;
            if (v.x > 0) pmask |= 1ull << (e + 0); else if (v.x == 0) nmask |= 1ull << (e + 0);
            if (v.y > 0) pmask |= 1ull << (e + 1); else if (v.y == 0) nmask |= 1ull << (e + 1);
            if (v.z > 0) pmask |= 1ull << (e + 2); else if (v.z == 0) nmask |= 1ull << (e + 2);
            if (v.w > 0) pmask |= 1ull << (e + 3); else if (v.w == 0) nmask |= 1ull << (e + 3);
        }
    }
    int cp = __popcll(pmask), cn = __popcll(nmask);
    int val  = (cp << 16) | cn;                // counts fit: NM < 65536
    int incl = val;
    #pragma unroll
    for (int off = 1; off < 64; off <<= 1) {
        int u = __shfl_up(incl, off, 64);
        if (lane >= off) incl += u;
    }
    if (lane == 63) wsum[wid] = incl;
    __syncthreads();
    int wbase = 0;
    #pragma unroll
    for (int w = 0; w < 4; ++w) if (w < wid) wbase += wsum[w];
    int tot  = wsum[0] + wsum[1] + wsum[2] + wsum[3];
    int excl = wbase + incl - val;
    int rp = excl >> 16, rn = excl & 0xffff;
    int posT = tot >> 16, negT = tot & 0xffff;
    int np = posT < 128 ? posT : 128;          // n_pos = min(pos_total, S/4)
    int nn = NS - np; if (nn > negT) nn = negT;

    if (base < NM) {
        #pragma unroll 4
        for (int e = 0; e < 64; ++e) {
            int idx = base + e;
            if ((pmask >> e) & 1ull) {
                if (rp < np) sampled[rp + (rn < nn ? rn : nn)] = idx;
                rp++;
            } else if ((nmask >> e) & 1ull) {
                if (rn < nn) sampled[rn + (rp < np ? rp : np)] = idx;
                rn++;
            }
        }
    }
    __syncthreads();
    // Fallback fill (unreachable with this data: pos>=NG, neg abundant):
    // unselected indices ascending, appended after the np+nn selected.
    if (tid == 0 && np + nn < NS) {
        int cpp = 0, cnn = 0, i = np + nn;
        for (int idx = 0; idx < NM && i < NS; ++idx) {
            int l = L[idx]; bool s;
            if (l > 0)       { s = cpp < np; cpp++; }
            else if (l == 0) { s = cnn < nn; cnn++; }
            else             { s = false; }
            if (!s) sampled[i++] = idx;
        }
    }
    __syncthreads();

    for (int i = tid; i < NS; i += 256) {
        int idx = sampled[i];
        int m   = match_in[(size_t)b * NM + idx];
        int l   = L[idx];
        float p0, p1, p2, p3;
        if (idx < NP) {
            const float* s = proposals + ((size_t)b * NP + idx) * 4;
            p0 = s[0]; p1 = s[1]; p2 = s[2]; p3 = s[3];
        } else {
            const float* s = gt_boxes + ((size_t)b * NG + (idx - NP)) * 4;
            p0 = s[0]; p1 = s[1]; p2 = s[2]; p3 = s[3];
        }
        const float* rf = gt_boxes + ((size_t)b * NG + m) * 4;
        float r0 = rf[0], r1 = rf[1], r2 = rf[2], r3 = rf[3];

        float pw = p2 - p0, ph = p3 - p1;
        float px = p0 + 0.5f * pw, py = p1 + 0.5f * ph;
        float gw = r2 - r0, gh = r3 - r1;
        float gx = r0 + 0.5f * gw, gy = r1 + 0.5f * gh;

        float* o = regt_out + ((size_t)b * NS + i) * 5;
        o[0] = 10.0f * (gx - px) / pw;
        o[1] = 10.0f * (gy - py) / ph;
        o[2] = 5.0f * logf(gw / pw);
        o[3] = 5.0f * logf(gh / ph);
        o[4] = gt_thetas[b * NG + m];
        labels_out[b * NS + i] = l;
    }
}

// ---------------------------------------------------------------------------
// Kernel 3: fused CE (log-softmax over 91) + smooth-L1 box loss.
// grid = LOSS_BLOCKS x 256 (4 waves). One wave per row, grid-stride over
// rows; per-block float2 partial to ws (NO atomics -> deterministic).
// ---------------------------------------------------------------------------
__global__ void loss_kernel(const float* __restrict__ logits,     // [N, 91]
                            const float* __restrict__ boxreg,     // [N, 455]
                            const int*   __restrict__ labels,     // [N]
                            const float* __restrict__ regt,       // [N, 5]
                            float2* __restrict__ partials)        // [LOSS_BLOCKS]
{
    const int wave  = threadIdx.x >> 6;
    const int lane  = threadIdx.x & 63;
    const int gwave = blockIdx.x * 4 + wave;          // 0 .. 4*LOSS_BLOCKS-1
    const int NWAVE = LOSS_BLOCKS * 4;
    const int N     = NB * NS;

    float cls_acc = 0.0f, box_acc = 0.0f;

    for (int r = gwave; r < N; r += NWAVE) {
        const float* row = logits + (size_t)r * NCLS;
        float a = (lane < NCLS)      ? row[lane]      : -3.0e38f;
        float c = (lane + 64 < NCLS) ? row[lane + 64] : -3.0e38f;
        float mx = fmaxf(a, c);
        #pragma unroll
        for (int o = 32; o; o >>= 1) mx = fmaxf(mx, __shfl_xor(mx, o, 64));
        float s = 0.0f;
        if (lane < NCLS)      s += expf(a - mx);
        if (lane + 64 < NCLS) s += expf(c - mx);
        #pragma unroll
        for (int o = 32; o; o >>= 1) s += __shfl_xor(s, o, 64);

        if (lane == 0) {
            int lab = labels[r];
            float xl = row[lab];
            cls_acc += -(xl - mx - logf(s));
            if (lab > 0) {
                const float* pr = boxreg + (size_t)r * (NCLS * 5) + lab * 5;
                const float* tg = regt + (size_t)r * 5;
                #pragma unroll
                for (int k = 0; k < 5; ++k) {
                    float d  = pr[k] - tg[k];
                    float ad = fabsf(d);
                    box_acc += (ad < SL1_BETA) ? 0.5f * d * d / SL1_BETA : ad - 0.5f * SL1_BETA;
                }
            }
        }
    }

    __shared__ float cpart[4], bpart[4];
    if (lane == 0) { cpart[wave] = cls_acc; bpart[wave] = box_acc; }
    __syncthreads();
    if (threadIdx.x == 0) {
        partials[blockIdx.x] = make_float2(cpart[0] + cpart[1] + cpart[2] + cpart[3],
                                           bpart[0] + bpart[1] + bpart[2] + bpart[3]);
    }
}

// ---------------------------------------------------------------------------
// Kernel 4: reduce LOSS_BLOCKS float2 partials -> 2 outputs. 1 block, 256 thr.
// ---------------------------------------------------------------------------
__global__ void final_kernel(const float2* __restrict__ partials,
                             float* __restrict__ out)
{
    const int tid  = threadIdx.x;
    const int lane = tid & 63;
    const int wid  = tid >> 6;
    float2 v = (tid < LOSS_BLOCKS) ? partials[tid] : make_float2(0.f, 0.f);
    float c = v.x, bx = v.y;
    #pragma unroll
    for (int o = 32; o; o >>= 1) {
        c  += __shfl_xor(c, o, 64);
        bx += __shfl_xor(bx, o, 64);
    }
    __shared__ float cc[4], bb[4];
    if (lane == 0) { cc[wid] = c; bb[wid] = bx; }
    __syncthreads();
    if (tid == 0) {
        const float invN = 1.0f / (float)(NB * NS);
        out[0] = (cc[0] + cc[1] + cc[2] + cc[3]) * invN;
        out[1] = (bb[0] + bb[1] + bb[2] + bb[3]) * invN;
    }
}

// ---------------------------------------------------------------------------
extern "C" void kernel_launch(void* const* d_in, const int* in_sizes, int n_in,
                              void* d_out, int out_size, void* d_ws, size_t ws_size,
                              hipStream_t stream)
{
    const float* class_logits   = (const float*)d_in[0];  // [NB*NS, 91]
    const float* box_regression = (const float*)d_in[1];  // [NB*NS, 455]
    const float* proposals      = (const float*)d_in[2];  // [NB, NP, 4]
    const float* gt_boxes       = (const float*)d_in[3];  // [NB, NG, 4]
    const float* gt_thetas      = (const float*)d_in[4];  // [NB, NG]
    const int*   gt_labels      = (const int*)d_in[5];    // [NB, NG]
    float* out = (float*)d_out;

    char* ws = (char*)d_ws;
    float2* partials = (float2*)ws;                        // LOSS_BLOCKS float2
    int* lblw   = (int*)(ws + LOSS_BLOCKS * sizeof(float2));
    int* matw   = lblw + (size_t)NB * NM;                  // NB*NM
    int* labs   = matw + (size_t)NB * NM;                  // NB*NS
    float* regt = (float*)(labs + (size_t)NB * NS);        // NB*NS*5

    hipLaunchKernelGGL(match_kernel, dim3((NM + 255) / 256, NB), dim3(256), 0, stream,
                       proposals, gt_boxes, gt_labels, lblw, matw);
    hipLaunchKernelGGL(sample_kernel, dim3(NB), dim3(256), 0, stream,
                       proposals, gt_boxes, gt_thetas, lblw, matw, labs, regt);
    hipLaunchKernelGGL(loss_kernel, dim3(LOSS_BLOCKS), dim3(256), 0, stream,
                       class_logits, box_regression, labs, regt, partials);
    hipLaunchKernelGGL(final_kernel, dim3(1), dim3(256), 0, stream, partials, out);
}